// Round 6
// baseline (657.716 us; speedup 1.0000x reference)
//
#include <hip/hip_runtime.h>

#define D 64
#define F 128
#define NBMAX 256
#define DB 128  // degree buckets

typedef unsigned int uint;
typedef unsigned short ushort;
typedef short s16x8 __attribute__((ext_vector_type(8)));
typedef float f32x4 __attribute__((ext_vector_type(4)));

__device__ __forceinline__ float bf16lo(uint u) { return __uint_as_float(u << 16); }
__device__ __forceinline__ float bf16hi(uint u) { return __uint_as_float(u & 0xFFFF0000u); }
__device__ __forceinline__ ushort f2bf16(float f) {
    uint u = __float_as_uint(f);
    u += 0x7FFFu + ((u >> 16) & 1u);   // RNE
    return (ushort)(u >> 16);
}
__device__ __forceinline__ uint pk2bf(float lo, float hi) {
    return (uint)f2bf16(lo) | ((uint)f2bf16(hi) << 16);
}

// ================= bucketed CSR build (N <= 65536) =================

__global__ __launch_bounds__(256) void bucket_hist(const int* __restrict__ dst,
                                                   int* __restrict__ gb, int E, int nb) {
    __shared__ int h[NBMAX];
    for (int t = threadIdx.x; t < nb; t += 256) h[t] = 0;
    __syncthreads();
    int start = blockIdx.x * 4096;
    int end   = start + 4096 < E ? start + 4096 : E;
    for (int i = start + threadIdx.x; i < end; i += 256)
        atomicAdd(&h[dst[i] >> 8], 1);
    __syncthreads();
    for (int t = threadIdx.x; t < nb; t += 256)
        if (h[t]) atomicAdd(&gb[t], h[t]);
}

__global__ void bucket_scan(const int* __restrict__ gb, int* __restrict__ gboff,
                            int* __restrict__ gcur, int nb) {
    if (threadIdx.x == 0) {
        int s = 0;
        for (int b = 0; b < nb; ++b) { gboff[b] = s; gcur[b] = s; s += gb[b]; }
        gboff[nb] = s;
    }
}

__global__ __launch_bounds__(256) void bucket_scatter(const int* __restrict__ src,
                                                      const int* __restrict__ dst,
                                                      int* __restrict__ gcur,
                                                      int* __restrict__ packed, int E, int nb) {
    __shared__ int h[NBMAX], base[NBMAX], lcur[NBMAX];
    for (int t = threadIdx.x; t < nb; t += 256) h[t] = 0;
    __syncthreads();
    int start = blockIdx.x * 4096;
    int end   = start + 4096 < E ? start + 4096 : E;
    for (int i = start + threadIdx.x; i < end; i += 256)
        atomicAdd(&h[dst[i] >> 8], 1);
    __syncthreads();
    for (int t = threadIdx.x; t < nb; t += 256) {
        base[t] = h[t] ? atomicAdd(&gcur[t], h[t]) : 0;
        lcur[t] = 0;
    }
    __syncthreads();
    for (int i = start + threadIdx.x; i < end; i += 256) {
        int d = dst[i];
        int b = d >> 8;
        int pos = base[b] + atomicAdd(&lcur[b], 1);
        packed[pos] = (src[i] << 8) | (d & 255);
    }
}

__global__ __launch_bounds__(256) void bucket_deg(const int* __restrict__ gboff,
                                                  const int* __restrict__ packed,
                                                  int* __restrict__ deg, int N) {
    __shared__ int h[NBMAX];
    int b = blockIdx.x;
    h[threadIdx.x] = 0;
    __syncthreads();
    int st = gboff[b], en = gboff[b + 1];
    for (int i = st + threadIdx.x; i < en; i += 256)
        atomicAdd(&h[packed[i] & 255], 1);
    __syncthreads();
    int node = (b << 8) + threadIdx.x;
    if (node < N) deg[node] = h[threadIdx.x];
}

// bucket_fill remaps src -> rank[src] (relabeled space)
__global__ __launch_bounds__(256) void bucket_fill(const int* __restrict__ gboff,
                                                   const int* __restrict__ packed,
                                                   const int* __restrict__ row_ptr,
                                                   const int* __restrict__ rank,
                                                   int* __restrict__ col, int N) {
    __shared__ int lcur[NBMAX];
    int b = blockIdx.x;
    int node = (b << 8) + threadIdx.x;
    lcur[threadIdx.x] = (node < N) ? row_ptr[node] : 0;
    __syncthreads();
    int st = gboff[b], en = gboff[b + 1];
    for (int i = st + threadIdx.x; i < en; i += 256) {
        int p = packed[i];
        int pos = atomicAdd(&lcur[p & 255], 1);
        col[pos] = rank[p >> 8];
    }
}

// ================= fallback CSR build (N > 65536) =================

__global__ void count_deg_kernel(const int* __restrict__ dst, int* __restrict__ deg, int E) {
    int i = blockIdx.x * blockDim.x + threadIdx.x;
    if (i < E) atomicAdd(&deg[dst[i]], 1);
}

__global__ void fill_kernel(const int* __restrict__ src, const int* __restrict__ dst,
                            int* __restrict__ cursor, const int* __restrict__ rank,
                            int* __restrict__ col, int E) {
    int i = blockIdx.x * blockDim.x + threadIdx.x;
    if (i < E) {
        int d_ = dst[i];
        int pos = atomicAdd(&cursor[d_], 1);
        col[pos] = rank[src[i]];
    }
}

// ================= degree sort: perm (relabeled->orig), rank (orig->relabeled) =================

__global__ __launch_bounds__(256) void dsort_hist(const int* __restrict__ deg,
                                                  int* __restrict__ dh, int N) {
    __shared__ int h[DB];
    if (threadIdx.x < DB) h[threadIdx.x] = 0;
    __syncthreads();
    int start = blockIdx.x * 4096;
    int end   = start + 4096 < N ? start + 4096 : N;
    for (int i = start + threadIdx.x; i < end; i += 256) {
        int d = deg[i];
        atomicAdd(&h[d < DB - 1 ? d : DB - 1], 1);
    }
    __syncthreads();
    if (threadIdx.x < DB && h[threadIdx.x]) atomicAdd(&dh[threadIdx.x], h[threadIdx.x]);
}

__global__ void dsort_scan(const int* __restrict__ dh, int* __restrict__ dcur) {
    if (threadIdx.x == 0) {
        int s = 0;
        for (int b = 0; b < DB; ++b) { dcur[b] = s; s += dh[b]; }
    }
}

__global__ __launch_bounds__(256) void dsort_scatter(const int* __restrict__ deg,
                                                     int* __restrict__ dcur,
                                                     int* __restrict__ perm,
                                                     int* __restrict__ rank, int N) {
    __shared__ int h[DB], base[DB], lc[DB];
    if (threadIdx.x < DB) h[threadIdx.x] = 0;
    __syncthreads();
    int start = blockIdx.x * 4096;
    int end   = start + 4096 < N ? start + 4096 : N;
    for (int i = start + threadIdx.x; i < end; i += 256) {
        int d = deg[i];
        atomicAdd(&h[d < DB - 1 ? d : DB - 1], 1);
    }
    __syncthreads();
    if (threadIdx.x < DB) {
        base[threadIdx.x] = h[threadIdx.x] ? atomicAdd(&dcur[threadIdx.x], h[threadIdx.x]) : 0;
        lc[threadIdx.x] = 0;
    }
    __syncthreads();
    for (int i = start + threadIdx.x; i < end; i += 256) {
        int d = deg[i];
        int b = d < DB - 1 ? d : DB - 1;
        int pos = base[b] + atomicAdd(&lc[b], 1);
        perm[pos] = i;
        rank[i] = pos;
    }
}

// ================= row_ptr scan (exact, unpadded) =================

__global__ __launch_bounds__(1024) void scan_kernel(const int* __restrict__ deg,
                                                    int* __restrict__ row_ptr, int n) {
    __shared__ int wsum[16];
    int lane = threadIdx.x & 63;
    int wid  = threadIdx.x >> 6;
    int carry = 0;
    const int CH = 4096;
    for (int base = 0; base < n; base += CH) {
        int i0 = base + (int)threadIdx.x * 4;
        int v0 = (i0     < n) ? deg[i0]     : 0;
        int v1 = (i0 + 1 < n) ? deg[i0 + 1] : 0;
        int v2 = (i0 + 2 < n) ? deg[i0 + 2] : 0;
        int v3 = (i0 + 3 < n) ? deg[i0 + 3] : 0;
        int p0 = v0, p1 = p0 + v1, p2 = p1 + v2, p3 = p2 + v3;
        int tsum = p3;
        int s = tsum;
        #pragma unroll
        for (int off = 1; off < 64; off <<= 1) {
            int t = __shfl_up(s, off);
            if (lane >= off) s += t;
        }
        if (lane == 63) wsum[wid] = s;
        __syncthreads();
        int wbase = 0, chunk_total = 0;
        #pragma unroll
        for (int w = 0; w < 16; ++w) {
            int t = wsum[w];
            chunk_total += t;
            if (w < wid) wbase += t;
        }
        __syncthreads();
        int ex = carry + wbase + (s - tsum);
        if (i0     < n) row_ptr[i0 + 1] = ex + p0;
        if (i0 + 1 < n) row_ptr[i0 + 2] = ex + p1;
        if (i0 + 2 < n) row_ptr[i0 + 3] = ex + p2;
        if (i0 + 3 < n) row_ptr[i0 + 4] = ex + p3;
        carry += chunk_total;
    }
    if (threadIdx.x == 0) row_ptr[0] = 0;
}

// ================= Wx via MFMA + fused emb1 init (relabeled rows) =================

__global__ __launch_bounds__(256) void wx_mfma_kernel(const float* __restrict__ x,
                                                      const float* __restrict__ W1,
                                                      const float* __restrict__ b1,
                                                      const float* __restrict__ b2,
                                                      const int* __restrict__ perm,
                                                      float* __restrict__ Wx,
                                                      ushort* __restrict__ emb, int N) {
    int lane = threadIdx.x & 63;
    int wv = blockIdx.x * 4 + (threadIdx.x >> 6);
    int nwaves = gridDim.x * 4;
    int r16 = lane & 15;
    int kg  = lane >> 4;

    s16x8 bf[4][4];
    #pragma unroll
    for (int nt = 0; nt < 4; ++nt) {
        const float* wrow = W1 + (size_t)(nt * 16 + r16) * F;
        #pragma unroll
        for (int ks = 0; ks < 4; ++ks) {
            const float4* p = reinterpret_cast<const float4*>(wrow + ks * 32 + kg * 8);
            float4 f0 = p[0], f1 = p[1];
            union { s16x8 v; uint u[4]; } t;
            t.u[0] = pk2bf(f0.x, f0.y); t.u[1] = pk2bf(f0.z, f0.w);
            t.u[2] = pk2bf(f1.x, f1.y); t.u[3] = pk2bf(f1.z, f1.w);
            bf[nt][ks] = t.v;
        }
    }
    float b1v[4], b2v[4];
    #pragma unroll
    for (int nt = 0; nt < 4; ++nt) {
        b1v[nt] = b1[nt * 16 + r16];
        b2v[nt] = b2[nt * 16 + r16];
    }

    int ntiles = (N + 15) >> 4;
    for (int tile = wv; tile < ntiles; tile += nwaves) {
        int row0 = tile << 4;
        int arow = row0 + r16;
        if (arow >= N) arow = N - 1;
        int orig = perm[arow];
        s16x8 af[4];
        #pragma unroll
        for (int ks = 0; ks < 4; ++ks) {
            const float4* p = reinterpret_cast<const float4*>(x + (size_t)orig * F + ks * 32 + kg * 8);
            float4 f0 = p[0], f1 = p[1];
            union { s16x8 v; uint u[4]; } t;
            t.u[0] = pk2bf(f0.x, f0.y); t.u[1] = pk2bf(f0.z, f0.w);
            t.u[2] = pk2bf(f1.x, f1.y); t.u[3] = pk2bf(f1.z, f1.w);
            af[ks] = t.v;
        }
        #pragma unroll
        for (int nt = 0; nt < 4; ++nt) {
            f32x4 acc = {0.f, 0.f, 0.f, 0.f};
            #pragma unroll
            for (int ks = 0; ks < 4; ++ks)
                acc = __builtin_amdgcn_mfma_f32_16x16x32_bf16(af[ks], bf[nt][ks], acc, 0, 0, 0);
            int outd = nt * 16 + r16;
            #pragma unroll
            for (int r = 0; r < 4; ++r) {
                int node = row0 + kg * 4 + r;
                if (node < N) {
                    float wxv = acc[r] + b1v[nt];
                    Wx[(size_t)node * D + outd] = wxv;
                    float e = wxv + b2v[nt];
                    emb[(size_t)node * D + outd] = f2bf16(e > 0.f ? e : 0.f);
                }
            }
        }
    }
}

// ================= fused iteration: 16 nodes/wave, MFMA matvec =================
// lane l: r=l&15 (node in tile), a=l>>4. Gather agg for node r into dims
// {8a..8a+7} (frag0) and {32+8a..+7} (frag1), f32. Then D^T = W2(A) x agg(B):
// 4 tiles x 2 k-frags = 8 MFMAs. D: col=r (node), row=4a+reg (dim within tile).

__global__ __launch_bounds__(256) void step_kernel(const ushort* __restrict__ emb_in,
                                                   ushort* __restrict__ emb_out,
                                                   const float* __restrict__ Wx,
                                                   const float* __restrict__ W2,
                                                   const float* __restrict__ b2,
                                                   const int* __restrict__ row_ptr,
                                                   const int* __restrict__ col,
                                                   const int* __restrict__ perm, int N) {
    int lane = threadIdx.x & 63;
    int w = threadIdx.x >> 6;
    int r = lane & 15;
    int a = lane >> 4;

    // A fragments: af[t][f] = W2[16t + r][32f + 8a .. +7] as bf16
    s16x8 af[4][2];
    #pragma unroll
    for (int t = 0; t < 4; ++t)
        #pragma unroll
        for (int f = 0; f < 2; ++f) {
            const float4* p = reinterpret_cast<const float4*>(W2 + (size_t)(t * 16 + r) * D + f * 32 + a * 8);
            float4 f0 = p[0], f1 = p[1];
            union { s16x8 v; uint u[4]; } tt;
            tt.u[0] = pk2bf(f0.x, f0.y); tt.u[1] = pk2bf(f0.z, f0.w);
            tt.u[2] = pk2bf(f1.x, f1.y); tt.u[3] = pk2bf(f1.z, f1.w);
            af[t][f] = tt.v;
        }
    float4 b2v[4];
    #pragma unroll
    for (int t = 0; t < 4; ++t)
        b2v[t] = *reinterpret_cast<const float4*>(b2 + t * 16 + a * 4);

    int ntiles = (N + 15) >> 4;
    int tile = blockIdx.x * 4 + w;
    if (tile >= ntiles) return;

    int rg = tile * 16 + r;
    int rgc = rg < N ? rg : N - 1;
    int node = perm[rgc];
    int rp = row_ptr[node];
    int degr = row_ptr[node + 1] - rp;
    if (rg >= N) degr = 0;
    int maxd = degr;
    #pragma unroll
    for (int off = 1; off < 16; off <<= 1) {
        int o = __shfl_xor(maxd, off);
        maxd = o > maxd ? o : maxd;
    }

    float acc0[8] = {0.f, 0.f, 0.f, 0.f, 0.f, 0.f, 0.f, 0.f};
    float acc1[8] = {0.f, 0.f, 0.f, 0.f, 0.f, 0.f, 0.f, 0.f};

    if (maxd > 0) {
        int u0 = (0 < degr) ? col[rp] : N;
        int u1 = (1 < degr) ? col[rp + 1] : N;
        uint4 q00 = *reinterpret_cast<const uint4*>(emb_in + ((size_t)u0 << 6) + (a << 3));
        uint4 q01 = *reinterpret_cast<const uint4*>(emb_in + ((size_t)u0 << 6) + 32 + (a << 3));
        uint4 q10 = *reinterpret_cast<const uint4*>(emb_in + ((size_t)u1 << 6) + (a << 3));
        uint4 q11 = *reinterpret_cast<const uint4*>(emb_in + ((size_t)u1 << 6) + 32 + (a << 3));
        for (int k = 0; k < maxd; ++k) {
            int un = (k + 2 < degr) ? col[rp + k + 2] : N;
            uint4 p0 = *reinterpret_cast<const uint4*>(emb_in + ((size_t)un << 6) + (a << 3));
            uint4 p1 = *reinterpret_cast<const uint4*>(emb_in + ((size_t)un << 6) + 32 + (a << 3));
            acc0[0] += bf16lo(q00.x); acc0[1] += bf16hi(q00.x);
            acc0[2] += bf16lo(q00.y); acc0[3] += bf16hi(q00.y);
            acc0[4] += bf16lo(q00.z); acc0[5] += bf16hi(q00.z);
            acc0[6] += bf16lo(q00.w); acc0[7] += bf16hi(q00.w);
            acc1[0] += bf16lo(q01.x); acc1[1] += bf16hi(q01.x);
            acc1[2] += bf16lo(q01.y); acc1[3] += bf16hi(q01.y);
            acc1[4] += bf16lo(q01.z); acc1[5] += bf16hi(q01.z);
            acc1[6] += bf16lo(q01.w); acc1[7] += bf16hi(q01.w);
            q00 = q10; q01 = q11; q10 = p0; q11 = p1;
        }
    }

    // pack agg to bf16 B-fragments
    union { s16x8 v; uint u[4]; } B0, B1;
    B0.u[0] = pk2bf(acc0[0], acc0[1]); B0.u[1] = pk2bf(acc0[2], acc0[3]);
    B0.u[2] = pk2bf(acc0[4], acc0[5]); B0.u[3] = pk2bf(acc0[6], acc0[7]);
    B1.u[0] = pk2bf(acc1[0], acc1[1]); B1.u[1] = pk2bf(acc1[2], acc1[3]);
    B1.u[2] = pk2bf(acc1[4], acc1[5]); B1.u[3] = pk2bf(acc1[6], acc1[7]);

    f32x4 d0 = {0.f, 0.f, 0.f, 0.f}, d1 = {0.f, 0.f, 0.f, 0.f};
    f32x4 d2 = {0.f, 0.f, 0.f, 0.f}, d3 = {0.f, 0.f, 0.f, 0.f};
    d0 = __builtin_amdgcn_mfma_f32_16x16x32_bf16(af[0][0], B0.v, d0, 0, 0, 0);
    d1 = __builtin_amdgcn_mfma_f32_16x16x32_bf16(af[1][0], B0.v, d1, 0, 0, 0);
    d2 = __builtin_amdgcn_mfma_f32_16x16x32_bf16(af[2][0], B0.v, d2, 0, 0, 0);
    d3 = __builtin_amdgcn_mfma_f32_16x16x32_bf16(af[3][0], B0.v, d3, 0, 0, 0);
    d0 = __builtin_amdgcn_mfma_f32_16x16x32_bf16(af[0][1], B1.v, d0, 0, 0, 0);
    d1 = __builtin_amdgcn_mfma_f32_16x16x32_bf16(af[1][1], B1.v, d1, 0, 0, 0);
    d2 = __builtin_amdgcn_mfma_f32_16x16x32_bf16(af[2][1], B1.v, d2, 0, 0, 0);
    d3 = __builtin_amdgcn_mfma_f32_16x16x32_bf16(af[3][1], B1.v, d3, 0, 0, 0);

    if (rg < N) {
        const float* wxp = Wx + ((size_t)rg << 6);
        ushort* op = emb_out + ((size_t)rg << 6);
        #pragma unroll
        for (int t = 0; t < 4; ++t) {
            float4 wx4 = *reinterpret_cast<const float4*>(wxp + t * 16 + a * 4);
            f32x4 dd = (t == 0) ? d0 : (t == 1) ? d1 : (t == 2) ? d2 : d3;
            float e0 = wx4.x + b2v[t].x + dd[0];
            float e1 = wx4.y + b2v[t].y + dd[1];
            float e2 = wx4.z + b2v[t].z + dd[2];
            float e3 = wx4.w + b2v[t].w + dd[3];
            e0 = e0 > 0.f ? e0 : 0.f; e1 = e1 > 0.f ? e1 : 0.f;
            e2 = e2 > 0.f ? e2 : 0.f; e3 = e3 > 0.f ? e3 : 0.f;
            uint2 st;
            st.x = pk2bf(e0, e1);
            st.y = pk2bf(e2, e3);
            *reinterpret_cast<uint2*>(op + t * 16 + a * 4) = st;
        }
    }
}

// ================= final: out[d] = sum_v emb[v][d] =================

__global__ __launch_bounds__(256) void reduce_kernel(const ushort* __restrict__ emb,
                                                     float* __restrict__ out, int N) {
    int lane = threadIdx.x & 63;
    int wid  = threadIdx.x >> 6;
    float acc = 0.f;
    int nw = gridDim.x * 4;
    for (int v = blockIdx.x * 4 + wid; v < N; v += nw)
        acc += __uint_as_float((uint)emb[(size_t)v * D + lane] << 16);
    __shared__ float red[256];
    red[threadIdx.x] = acc;
    __syncthreads();
    if (threadIdx.x < 64) {
        float sum = red[threadIdx.x] + red[threadIdx.x + 64] +
                    red[threadIdx.x + 128] + red[threadIdx.x + 192];
        atomicAdd(&out[threadIdx.x], sum);
    }
}

extern "C" void kernel_launch(void* const* d_in, const int* in_sizes, int n_in,
                              void* d_out, int out_size, void* d_ws, size_t ws_size,
                              hipStream_t stream) {
    const float* x    = (const float*)d_in[0];
    const float* W1   = (const float*)d_in[1];
    const float* b1   = (const float*)d_in[2];
    const float* W2   = (const float*)d_in[3];
    const float* b2   = (const float*)d_in[4];
    const int*   esrc = (const int*)d_in[5];
    const int*   edst = (const int*)d_in[6];
    int N = in_sizes[0] / F;
    int E = in_sizes[5];
    float* out = (float*)d_out;

    char* ws = (char*)d_ws;
    size_t off = 0;
    auto alloc = [&](size_t bytes) -> char* {
        char* p = ws + off;
        off += (bytes + 255) & ~(size_t)255;
        return p;
    };
    float*  Wx      = (float*)alloc((size_t)N * D * 4);
    ushort* embA    = (ushort*)alloc(((size_t)N + 1) * D * 2);
    ushort* embB    = (ushort*)alloc(((size_t)N + 1) * D * 2);
    int*    row_ptr = (int*)alloc(((size_t)N + 1) * 4);
    int*    deg     = (int*)alloc((size_t)N * 4);
    int*    col     = (int*)alloc((size_t)E * 4);
    int*    packed  = (int*)alloc((size_t)E * 4);
    int*    perm    = (int*)alloc(((size_t)N + 16) * 4);
    int*    rank    = (int*)alloc((size_t)N * 4);
    int*    gb      = (int*)alloc((NBMAX + 1) * 4);
    int*    gboff   = (int*)alloc((NBMAX + 1) * 4);
    int*    gcur    = (int*)alloc((NBMAX + 1) * 4);
    int*    dh      = (int*)alloc(DB * 4);
    int*    dcur    = (int*)alloc(DB * 4);
    int*    cursor  = (int*)alloc((size_t)N * 4);  // fallback path only

    hipMemsetAsync(out, 0, (size_t)out_size * 4, stream);
    hipMemsetAsync(embA + (size_t)N * D, 0, D * 2, stream);
    hipMemsetAsync(embB + (size_t)N * D, 0, D * 2, stream);
    hipMemsetAsync(dh, 0, DB * 4, stream);

    int nb = ((N - 1) >> 8) + 1;
    int nchunksE = (E + 4095) / 4096;
    int nchunksN = (N + 4095) / 4096;
    if (N <= 65536) {
        hipMemsetAsync(gb, 0, (size_t)nb * 4, stream);
        bucket_hist<<<nchunksE, 256, 0, stream>>>(edst, gb, E, nb);
        bucket_scan<<<1, 64, 0, stream>>>(gb, gboff, gcur, nb);
        bucket_scatter<<<nchunksE, 256, 0, stream>>>(esrc, edst, gcur, packed, E, nb);
        bucket_deg<<<nb, 256, 0, stream>>>(gboff, packed, deg, N);
        dsort_hist<<<nchunksN, 256, 0, stream>>>(deg, dh, N);
        dsort_scan<<<1, 64, 0, stream>>>(dh, dcur);
        dsort_scatter<<<nchunksN, 256, 0, stream>>>(deg, dcur, perm, rank, N);
        scan_kernel<<<1, 1024, 0, stream>>>(deg, row_ptr, N);
        bucket_fill<<<nb, 256, 0, stream>>>(gboff, packed, row_ptr, rank, col, N);
    } else {
        hipMemsetAsync(deg, 0, (size_t)N * 4, stream);
        count_deg_kernel<<<(E + 255) / 256, 256, 0, stream>>>(edst, deg, E);
        dsort_hist<<<nchunksN, 256, 0, stream>>>(deg, dh, N);
        dsort_scan<<<1, 64, 0, stream>>>(dh, dcur);
        dsort_scatter<<<nchunksN, 256, 0, stream>>>(deg, dcur, perm, rank, N);
        scan_kernel<<<1, 1024, 0, stream>>>(deg, row_ptr, N);
        hipMemcpyAsync(cursor, row_ptr, (size_t)N * 4, hipMemcpyDeviceToDevice, stream);
        fill_kernel<<<(E + 255) / 256, 256, 0, stream>>>(esrc, edst, cursor, rank, col, E);
    }

    wx_mfma_kernel<<<256, 256, 0, stream>>>(x, W1, b1, b2, perm, Wx, embA, N);

    int ntiles = (N + 15) >> 4;
    int sblocks = (ntiles + 3) / 4;
    ushort* pin = embA;
    ushort* pout = embB;
    for (int t = 1; t < 10; ++t) {
        step_kernel<<<sblocks, 256, 0, stream>>>(pin, pout, Wx, W2, b2, row_ptr, col, perm, N);
        ushort* tmp = pin; pin = pout; pout = tmp;
    }
    reduce_kernel<<<256, 256, 0, stream>>>(pin, out, N);
}

// Round 7
// 589.363 us; speedup vs baseline: 1.1160x; 1.1160x over previous
//
#include <hip/hip_runtime.h>

#define D 64
#define F 128
#define NBMAX 256
#define DB 128  // degree buckets

typedef unsigned int uint;
typedef unsigned short ushort;
typedef short s16x8 __attribute__((ext_vector_type(8)));
typedef float f32x4 __attribute__((ext_vector_type(4)));

__device__ __forceinline__ float bf16lo(uint u) { return __uint_as_float(u << 16); }
__device__ __forceinline__ float bf16hi(uint u) { return __uint_as_float(u & 0xFFFF0000u); }
__device__ __forceinline__ ushort f2bf16(float f) {
    uint u = __float_as_uint(f);
    u += 0x7FFFu + ((u >> 16) & 1u);   // RNE
    return (ushort)(u >> 16);
}
__device__ __forceinline__ uint pk2bf(float lo, float hi) {
    return (uint)f2bf16(lo) | ((uint)f2bf16(hi) << 16);
}

// ================= bucketed CSR build (N <= 65536) =================

__global__ __launch_bounds__(256) void bucket_hist(const int* __restrict__ dst,
                                                   int* __restrict__ gb, int E, int nb) {
    __shared__ int h[NBMAX];
    for (int t = threadIdx.x; t < nb; t += 256) h[t] = 0;
    __syncthreads();
    int start = blockIdx.x * 4096;
    int end   = start + 4096 < E ? start + 4096 : E;
    for (int i = start + threadIdx.x; i < end; i += 256)
        atomicAdd(&h[dst[i] >> 8], 1);
    __syncthreads();
    for (int t = threadIdx.x; t < nb; t += 256)
        if (h[t]) atomicAdd(&gb[t], h[t]);
}

__global__ void bucket_scan(const int* __restrict__ gb, int* __restrict__ gboff,
                            int* __restrict__ gcur, int nb) {
    if (threadIdx.x == 0) {
        int s = 0;
        for (int b = 0; b < nb; ++b) { gboff[b] = s; gcur[b] = s; s += gb[b]; }
        gboff[nb] = s;
    }
}

__global__ __launch_bounds__(256) void bucket_scatter(const int* __restrict__ src,
                                                      const int* __restrict__ dst,
                                                      int* __restrict__ gcur,
                                                      int* __restrict__ packed, int E, int nb) {
    __shared__ int h[NBMAX], base[NBMAX], lcur[NBMAX];
    for (int t = threadIdx.x; t < nb; t += 256) h[t] = 0;
    __syncthreads();
    int start = blockIdx.x * 4096;
    int end   = start + 4096 < E ? start + 4096 : E;
    for (int i = start + threadIdx.x; i < end; i += 256)
        atomicAdd(&h[dst[i] >> 8], 1);
    __syncthreads();
    for (int t = threadIdx.x; t < nb; t += 256) {
        base[t] = h[t] ? atomicAdd(&gcur[t], h[t]) : 0;
        lcur[t] = 0;
    }
    __syncthreads();
    for (int i = start + threadIdx.x; i < end; i += 256) {
        int d = dst[i];
        int b = d >> 8;
        int pos = base[b] + atomicAdd(&lcur[b], 1);
        packed[pos] = (src[i] << 8) | (d & 255);
    }
}

__global__ __launch_bounds__(256) void bucket_deg(const int* __restrict__ gboff,
                                                  const int* __restrict__ packed,
                                                  int* __restrict__ deg, int N) {
    __shared__ int h[NBMAX];
    int b = blockIdx.x;
    h[threadIdx.x] = 0;
    __syncthreads();
    int st = gboff[b], en = gboff[b + 1];
    for (int i = st + threadIdx.x; i < en; i += 256)
        atomicAdd(&h[packed[i] & 255], 1);
    __syncthreads();
    int node = (b << 8) + threadIdx.x;
    if (node < N) deg[node] = h[threadIdx.x];
}

// bucket_fill remaps src -> rank[src] (relabeled space)
__global__ __launch_bounds__(256) void bucket_fill(const int* __restrict__ gboff,
                                                   const int* __restrict__ packed,
                                                   const int* __restrict__ row_ptr,
                                                   const int* __restrict__ rank,
                                                   int* __restrict__ col, int N) {
    __shared__ int lcur[NBMAX];
    int b = blockIdx.x;
    int node = (b << 8) + threadIdx.x;
    lcur[threadIdx.x] = (node < N) ? row_ptr[node] : 0;
    __syncthreads();
    int st = gboff[b], en = gboff[b + 1];
    for (int i = st + threadIdx.x; i < en; i += 256) {
        int p = packed[i];
        int pos = atomicAdd(&lcur[p & 255], 1);
        col[pos] = rank[p >> 8];
    }
}

// ================= fallback CSR build (N > 65536) =================

__global__ void count_deg_kernel(const int* __restrict__ dst, int* __restrict__ deg, int E) {
    int i = blockIdx.x * blockDim.x + threadIdx.x;
    if (i < E) atomicAdd(&deg[dst[i]], 1);
}

__global__ void fill_kernel(const int* __restrict__ src, const int* __restrict__ dst,
                            int* __restrict__ cursor, const int* __restrict__ rank,
                            int* __restrict__ col, int E) {
    int i = blockIdx.x * blockDim.x + threadIdx.x;
    if (i < E) {
        int d_ = dst[i];
        int pos = atomicAdd(&cursor[d_], 1);
        col[pos] = rank[src[i]];
    }
}

// ================= degree sort: perm (relabeled->orig), rank (orig->relabeled) =================

__global__ __launch_bounds__(256) void dsort_hist(const int* __restrict__ deg,
                                                  int* __restrict__ dh, int N) {
    __shared__ int h[DB];
    if (threadIdx.x < DB) h[threadIdx.x] = 0;
    __syncthreads();
    int start = blockIdx.x * 4096;
    int end   = start + 4096 < N ? start + 4096 : N;
    for (int i = start + threadIdx.x; i < end; i += 256) {
        int d = deg[i];
        atomicAdd(&h[d < DB - 1 ? d : DB - 1], 1);
    }
    __syncthreads();
    if (threadIdx.x < DB && h[threadIdx.x]) atomicAdd(&dh[threadIdx.x], h[threadIdx.x]);
}

__global__ void dsort_scan(const int* __restrict__ dh, int* __restrict__ dcur) {
    if (threadIdx.x == 0) {
        int s = 0;
        for (int b = 0; b < DB; ++b) { dcur[b] = s; s += dh[b]; }
    }
}

__global__ __launch_bounds__(256) void dsort_scatter(const int* __restrict__ deg,
                                                     int* __restrict__ dcur,
                                                     int* __restrict__ perm,
                                                     int* __restrict__ rank, int N) {
    __shared__ int h[DB], base[DB], lc[DB];
    if (threadIdx.x < DB) h[threadIdx.x] = 0;
    __syncthreads();
    int start = blockIdx.x * 4096;
    int end   = start + 4096 < N ? start + 4096 : N;
    for (int i = start + threadIdx.x; i < end; i += 256) {
        int d = deg[i];
        atomicAdd(&h[d < DB - 1 ? d : DB - 1], 1);
    }
    __syncthreads();
    if (threadIdx.x < DB) {
        base[threadIdx.x] = h[threadIdx.x] ? atomicAdd(&dcur[threadIdx.x], h[threadIdx.x]) : 0;
        lc[threadIdx.x] = 0;
    }
    __syncthreads();
    for (int i = start + threadIdx.x; i < end; i += 256) {
        int d = deg[i];
        int b = d < DB - 1 ? d : DB - 1;
        int pos = base[b] + atomicAdd(&lc[b], 1);
        perm[pos] = i;
        rank[i] = pos;
    }
}

// ================= row_ptr scan (exact, unpadded) =================

__global__ __launch_bounds__(1024) void scan_kernel(const int* __restrict__ deg,
                                                    int* __restrict__ row_ptr, int n) {
    __shared__ int wsum[16];
    int lane = threadIdx.x & 63;
    int wid  = threadIdx.x >> 6;
    int carry = 0;
    const int CH = 4096;
    for (int base = 0; base < n; base += CH) {
        int i0 = base + (int)threadIdx.x * 4;
        int v0 = (i0     < n) ? deg[i0]     : 0;
        int v1 = (i0 + 1 < n) ? deg[i0 + 1] : 0;
        int v2 = (i0 + 2 < n) ? deg[i0 + 2] : 0;
        int v3 = (i0 + 3 < n) ? deg[i0 + 3] : 0;
        int p0 = v0, p1 = p0 + v1, p2 = p1 + v2, p3 = p2 + v3;
        int tsum = p3;
        int s = tsum;
        #pragma unroll
        for (int off = 1; off < 64; off <<= 1) {
            int t = __shfl_up(s, off);
            if (lane >= off) s += t;
        }
        if (lane == 63) wsum[wid] = s;
        __syncthreads();
        int wbase = 0, chunk_total = 0;
        #pragma unroll
        for (int w = 0; w < 16; ++w) {
            int t = wsum[w];
            chunk_total += t;
            if (w < wid) wbase += t;
        }
        __syncthreads();
        int ex = carry + wbase + (s - tsum);
        if (i0     < n) row_ptr[i0 + 1] = ex + p0;
        if (i0 + 1 < n) row_ptr[i0 + 2] = ex + p1;
        if (i0 + 2 < n) row_ptr[i0 + 3] = ex + p2;
        if (i0 + 3 < n) row_ptr[i0 + 4] = ex + p3;
        carry += chunk_total;
    }
    if (threadIdx.x == 0) row_ptr[0] = 0;
}

// ================= Wx via MFMA + fused emb1 init (relabeled rows) =================

__global__ __launch_bounds__(256) void wx_mfma_kernel(const float* __restrict__ x,
                                                      const float* __restrict__ W1,
                                                      const float* __restrict__ b1,
                                                      const float* __restrict__ b2,
                                                      const int* __restrict__ perm,
                                                      float* __restrict__ Wx,
                                                      ushort* __restrict__ emb, int N) {
    int lane = threadIdx.x & 63;
    int wv = blockIdx.x * 4 + (threadIdx.x >> 6);
    int nwaves = gridDim.x * 4;
    int r16 = lane & 15;
    int kg  = lane >> 4;

    s16x8 bf[4][4];
    #pragma unroll
    for (int nt = 0; nt < 4; ++nt) {
        const float* wrow = W1 + (size_t)(nt * 16 + r16) * F;
        #pragma unroll
        for (int ks = 0; ks < 4; ++ks) {
            const float4* p = reinterpret_cast<const float4*>(wrow + ks * 32 + kg * 8);
            float4 f0 = p[0], f1 = p[1];
            union { s16x8 v; uint u[4]; } t;
            t.u[0] = pk2bf(f0.x, f0.y); t.u[1] = pk2bf(f0.z, f0.w);
            t.u[2] = pk2bf(f1.x, f1.y); t.u[3] = pk2bf(f1.z, f1.w);
            bf[nt][ks] = t.v;
        }
    }
    float b1v[4], b2v[4];
    #pragma unroll
    for (int nt = 0; nt < 4; ++nt) {
        b1v[nt] = b1[nt * 16 + r16];
        b2v[nt] = b2[nt * 16 + r16];
    }

    int ntiles = (N + 15) >> 4;
    for (int tile = wv; tile < ntiles; tile += nwaves) {
        int row0 = tile << 4;
        int arow = row0 + r16;
        if (arow >= N) arow = N - 1;
        int orig = perm[arow];
        s16x8 af[4];
        #pragma unroll
        for (int ks = 0; ks < 4; ++ks) {
            const float4* p = reinterpret_cast<const float4*>(x + (size_t)orig * F + ks * 32 + kg * 8);
            float4 f0 = p[0], f1 = p[1];
            union { s16x8 v; uint u[4]; } t;
            t.u[0] = pk2bf(f0.x, f0.y); t.u[1] = pk2bf(f0.z, f0.w);
            t.u[2] = pk2bf(f1.x, f1.y); t.u[3] = pk2bf(f1.z, f1.w);
            af[ks] = t.v;
        }
        #pragma unroll
        for (int nt = 0; nt < 4; ++nt) {
            f32x4 acc = {0.f, 0.f, 0.f, 0.f};
            #pragma unroll
            for (int ks = 0; ks < 4; ++ks)
                acc = __builtin_amdgcn_mfma_f32_16x16x32_bf16(af[ks], bf[nt][ks], acc, 0, 0, 0);
            int outd = nt * 16 + r16;
            #pragma unroll
            for (int r = 0; r < 4; ++r) {
                int node = row0 + kg * 4 + r;
                if (node < N) {
                    float wxv = acc[r] + b1v[nt];
                    Wx[(size_t)node * D + outd] = wxv;
                    float e = wxv + b2v[nt];
                    emb[(size_t)node * D + outd] = f2bf16(e > 0.f ? e : 0.f);
                }
            }
        }
    }
}

// ================= fused iteration: 16 nodes/wave, MFMA matvec =================
// lane l: r=l&15 (node in tile), a=l>>4. Gather unrolled 4 neighbors/chunk,
// depth-2 prefetch (~8 uint4 in flight/lane). W2 fragments loaded AFTER the
// gather loop to keep hot-loop VGPR pressure low. Tiles dispatched in reverse
// (high-degree first) to kill the load-imbalance tail.

__global__ __launch_bounds__(256) void step_kernel(const ushort* __restrict__ emb_in,
                                                   ushort* __restrict__ emb_out,
                                                   const float* __restrict__ Wx,
                                                   const float* __restrict__ W2,
                                                   const float* __restrict__ b2,
                                                   const int* __restrict__ row_ptr,
                                                   const int* __restrict__ col,
                                                   const int* __restrict__ perm, int N) {
    int lane = threadIdx.x & 63;
    int w = threadIdx.x >> 6;
    int r = lane & 15;
    int a = lane >> 4;

    int ntiles = (N + 15) >> 4;
    int tile = ntiles - 1 - (blockIdx.x * 4 + w);  // reversed: high-degree first
    if (tile < 0) return;

    int rg = tile * 16 + r;
    int rgc = rg < N ? rg : N - 1;
    int node = perm[rgc];
    int rp = row_ptr[node];
    int degr = row_ptr[node + 1] - rp;
    if (rg >= N) degr = 0;
    int maxd = degr;
    #pragma unroll
    for (int off = 1; off < 16; off <<= 1) {
        int o = __shfl_xor(maxd, off);
        maxd = o > maxd ? o : maxd;
    }

    float acc0[8] = {0.f, 0.f, 0.f, 0.f, 0.f, 0.f, 0.f, 0.f};
    float acc1[8] = {0.f, 0.f, 0.f, 0.f, 0.f, 0.f, 0.f, 0.f};

    const ushort* base0 = emb_in + (a << 3);        // dims 8a..8a+7
    const ushort* base1 = emb_in + 32 + (a << 3);   // dims 32+8a..32+8a+7

    if (maxd > 0) {
        uint4 c0[4], c1[4];
        #pragma unroll
        for (int j = 0; j < 4; ++j) {
            int u = (j < degr) ? col[rp + j] : N;
            c0[j] = *reinterpret_cast<const uint4*>(base0 + ((size_t)u << 6));
            c1[j] = *reinterpret_cast<const uint4*>(base1 + ((size_t)u << 6));
        }
        int nch = (maxd + 3) >> 2;
        for (int c = 0; c < nch; ++c) {
            uint4 n0[4], n1[4];
            int kb = (c + 1) << 2;
            if (c + 1 < nch) {
                #pragma unroll
                for (int j = 0; j < 4; ++j) {
                    int u = (kb + j < degr) ? col[rp + kb + j] : N;
                    n0[j] = *reinterpret_cast<const uint4*>(base0 + ((size_t)u << 6));
                    n1[j] = *reinterpret_cast<const uint4*>(base1 + ((size_t)u << 6));
                }
            }
            #pragma unroll
            for (int j = 0; j < 4; ++j) {
                acc0[0] += bf16lo(c0[j].x); acc0[1] += bf16hi(c0[j].x);
                acc0[2] += bf16lo(c0[j].y); acc0[3] += bf16hi(c0[j].y);
                acc0[4] += bf16lo(c0[j].z); acc0[5] += bf16hi(c0[j].z);
                acc0[6] += bf16lo(c0[j].w); acc0[7] += bf16hi(c0[j].w);
                acc1[0] += bf16lo(c1[j].x); acc1[1] += bf16hi(c1[j].x);
                acc1[2] += bf16lo(c1[j].y); acc1[3] += bf16hi(c1[j].y);
                acc1[4] += bf16lo(c1[j].z); acc1[5] += bf16hi(c1[j].z);
                acc1[6] += bf16lo(c1[j].w); acc1[7] += bf16hi(c1[j].w);
            }
            #pragma unroll
            for (int j = 0; j < 4; ++j) { c0[j] = n0[j]; c1[j] = n1[j]; }
        }
    }

    // ---- epilogue: load W2 fragments now (keeps gather-loop VGPRs low) ----
    s16x8 af[4][2];
    #pragma unroll
    for (int t = 0; t < 4; ++t)
        #pragma unroll
        for (int f = 0; f < 2; ++f) {
            const float4* p = reinterpret_cast<const float4*>(W2 + (size_t)(t * 16 + r) * D + f * 32 + a * 8);
            float4 f0 = p[0], f1 = p[1];
            union { s16x8 v; uint u[4]; } tt;
            tt.u[0] = pk2bf(f0.x, f0.y); tt.u[1] = pk2bf(f0.z, f0.w);
            tt.u[2] = pk2bf(f1.x, f1.y); tt.u[3] = pk2bf(f1.z, f1.w);
            af[t][f] = tt.v;
        }
    float4 b2v[4];
    #pragma unroll
    for (int t = 0; t < 4; ++t)
        b2v[t] = *reinterpret_cast<const float4*>(b2 + t * 16 + a * 4);

    union { s16x8 v; uint u[4]; } B0, B1;
    B0.u[0] = pk2bf(acc0[0], acc0[1]); B0.u[1] = pk2bf(acc0[2], acc0[3]);
    B0.u[2] = pk2bf(acc0[4], acc0[5]); B0.u[3] = pk2bf(acc0[6], acc0[7]);
    B1.u[0] = pk2bf(acc1[0], acc1[1]); B1.u[1] = pk2bf(acc1[2], acc1[3]);
    B1.u[2] = pk2bf(acc1[4], acc1[5]); B1.u[3] = pk2bf(acc1[6], acc1[7]);

    f32x4 d0 = {0.f, 0.f, 0.f, 0.f}, d1 = {0.f, 0.f, 0.f, 0.f};
    f32x4 d2 = {0.f, 0.f, 0.f, 0.f}, d3 = {0.f, 0.f, 0.f, 0.f};
    d0 = __builtin_amdgcn_mfma_f32_16x16x32_bf16(af[0][0], B0.v, d0, 0, 0, 0);
    d1 = __builtin_amdgcn_mfma_f32_16x16x32_bf16(af[1][0], B0.v, d1, 0, 0, 0);
    d2 = __builtin_amdgcn_mfma_f32_16x16x32_bf16(af[2][0], B0.v, d2, 0, 0, 0);
    d3 = __builtin_amdgcn_mfma_f32_16x16x32_bf16(af[3][0], B0.v, d3, 0, 0, 0);
    d0 = __builtin_amdgcn_mfma_f32_16x16x32_bf16(af[0][1], B1.v, d0, 0, 0, 0);
    d1 = __builtin_amdgcn_mfma_f32_16x16x32_bf16(af[1][1], B1.v, d1, 0, 0, 0);
    d2 = __builtin_amdgcn_mfma_f32_16x16x32_bf16(af[2][1], B1.v, d2, 0, 0, 0);
    d3 = __builtin_amdgcn_mfma_f32_16x16x32_bf16(af[3][1], B1.v, d3, 0, 0, 0);

    if (rg < N) {
        const float* wxp = Wx + ((size_t)rg << 6);
        ushort* op = emb_out + ((size_t)rg << 6);
        #pragma unroll
        for (int t = 0; t < 4; ++t) {
            float4 wx4 = *reinterpret_cast<const float4*>(wxp + t * 16 + a * 4);
            f32x4 dd = (t == 0) ? d0 : (t == 1) ? d1 : (t == 2) ? d2 : d3;
            float e0 = wx4.x + b2v[t].x + dd[0];
            float e1 = wx4.y + b2v[t].y + dd[1];
            float e2 = wx4.z + b2v[t].z + dd[2];
            float e3 = wx4.w + b2v[t].w + dd[3];
            e0 = e0 > 0.f ? e0 : 0.f; e1 = e1 > 0.f ? e1 : 0.f;
            e2 = e2 > 0.f ? e2 : 0.f; e3 = e3 > 0.f ? e3 : 0.f;
            uint2 st;
            st.x = pk2bf(e0, e1);
            st.y = pk2bf(e2, e3);
            *reinterpret_cast<uint2*>(op + t * 16 + a * 4) = st;
        }
    }
}

// ================= final: out[d] = sum_v emb[v][d] =================

__global__ __launch_bounds__(256) void reduce_kernel(const ushort* __restrict__ emb,
                                                     float* __restrict__ out, int N) {
    int lane = threadIdx.x & 63;
    int wid  = threadIdx.x >> 6;
    float acc = 0.f;
    int nw = gridDim.x * 4;
    for (int v = blockIdx.x * 4 + wid; v < N; v += nw)
        acc += __uint_as_float((uint)emb[(size_t)v * D + lane] << 16);
    __shared__ float red[256];
    red[threadIdx.x] = acc;
    __syncthreads();
    if (threadIdx.x < 64) {
        float sum = red[threadIdx.x] + red[threadIdx.x + 64] +
                    red[threadIdx.x + 128] + red[threadIdx.x + 192];
        atomicAdd(&out[threadIdx.x], sum);
    }
}

extern "C" void kernel_launch(void* const* d_in, const int* in_sizes, int n_in,
                              void* d_out, int out_size, void* d_ws, size_t ws_size,
                              hipStream_t stream) {
    const float* x    = (const float*)d_in[0];
    const float* W1   = (const float*)d_in[1];
    const float* b1   = (const float*)d_in[2];
    const float* W2   = (const float*)d_in[3];
    const float* b2   = (const float*)d_in[4];
    const int*   esrc = (const int*)d_in[5];
    const int*   edst = (const int*)d_in[6];
    int N = in_sizes[0] / F;
    int E = in_sizes[5];
    float* out = (float*)d_out;

    char* ws = (char*)d_ws;
    size_t off = 0;
    auto alloc = [&](size_t bytes) -> char* {
        char* p = ws + off;
        off += (bytes + 255) & ~(size_t)255;
        return p;
    };
    float*  Wx      = (float*)alloc((size_t)N * D * 4);
    ushort* embA    = (ushort*)alloc(((size_t)N + 1) * D * 2);
    ushort* embB    = (ushort*)alloc(((size_t)N + 1) * D * 2);
    int*    row_ptr = (int*)alloc(((size_t)N + 1) * 4);
    int*    deg     = (int*)alloc((size_t)N * 4);
    int*    col     = (int*)alloc((size_t)E * 4);
    int*    packed  = (int*)alloc((size_t)E * 4);
    int*    perm    = (int*)alloc(((size_t)N + 16) * 4);
    int*    rank    = (int*)alloc((size_t)N * 4);
    int*    gb      = (int*)alloc((NBMAX + 1) * 4);
    int*    gboff   = (int*)alloc((NBMAX + 1) * 4);
    int*    gcur    = (int*)alloc((NBMAX + 1) * 4);
    int*    dh      = (int*)alloc(DB * 4);
    int*    dcur    = (int*)alloc(DB * 4);
    int*    cursor  = (int*)alloc((size_t)N * 4);  // fallback path only

    hipMemsetAsync(out, 0, (size_t)out_size * 4, stream);
    hipMemsetAsync(embA + (size_t)N * D, 0, D * 2, stream);
    hipMemsetAsync(embB + (size_t)N * D, 0, D * 2, stream);
    hipMemsetAsync(dh, 0, DB * 4, stream);

    int nb = ((N - 1) >> 8) + 1;
    int nchunksE = (E + 4095) / 4096;
    int nchunksN = (N + 4095) / 4096;
    if (N <= 65536) {
        hipMemsetAsync(gb, 0, (size_t)nb * 4, stream);
        bucket_hist<<<nchunksE, 256, 0, stream>>>(edst, gb, E, nb);
        bucket_scan<<<1, 64, 0, stream>>>(gb, gboff, gcur, nb);
        bucket_scatter<<<nchunksE, 256, 0, stream>>>(esrc, edst, gcur, packed, E, nb);
        bucket_deg<<<nb, 256, 0, stream>>>(gboff, packed, deg, N);
        dsort_hist<<<nchunksN, 256, 0, stream>>>(deg, dh, N);
        dsort_scan<<<1, 64, 0, stream>>>(dh, dcur);
        dsort_scatter<<<nchunksN, 256, 0, stream>>>(deg, dcur, perm, rank, N);
        scan_kernel<<<1, 1024, 0, stream>>>(deg, row_ptr, N);
        bucket_fill<<<nb, 256, 0, stream>>>(gboff, packed, row_ptr, rank, col, N);
    } else {
        hipMemsetAsync(deg, 0, (size_t)N * 4, stream);
        count_deg_kernel<<<(E + 255) / 256, 256, 0, stream>>>(edst, deg, E);
        dsort_hist<<<nchunksN, 256, 0, stream>>>(deg, dh, N);
        dsort_scan<<<1, 64, 0, stream>>>(dh, dcur);
        dsort_scatter<<<nchunksN, 256, 0, stream>>>(deg, dcur, perm, rank, N);
        scan_kernel<<<1, 1024, 0, stream>>>(deg, row_ptr, N);
        hipMemcpyAsync(cursor, row_ptr, (size_t)N * 4, hipMemcpyDeviceToDevice, stream);
        fill_kernel<<<(E + 255) / 256, 256, 0, stream>>>(esrc, edst, cursor, rank, col, E);
    }

    wx_mfma_kernel<<<256, 256, 0, stream>>>(x, W1, b1, b2, perm, Wx, embA, N);

    int ntiles = (N + 15) >> 4;
    int sblocks = (ntiles + 3) / 4;
    ushort* pin = embA;
    ushort* pout = embB;
    for (int t = 1; t < 10; ++t) {
        step_kernel<<<sblocks, 256, 0, stream>>>(pin, pout, Wx, W2, b2, row_ptr, col, perm, N);
        ushort* tmp = pin; pin = pout; pout = tmp;
    }
    reduce_kernel<<<256, 256, 0, stream>>>(pin, out, N);
}